// Round 9
// baseline (77.472 us; speedup 1.0000x reference)
//
#include <hip/hip_runtime.h>
#include <hip/hip_bf16.h>
#include <math.h>

#define D 8192
#define NT 256

// ---------- wave (64-lane) shuffle reduction ----------
__device__ __forceinline__ float wave_sum(float v) {
    #pragma unroll
    for (int o = 32; o > 0; o >>= 1) v += __shfl_xor(v, o, 64);
    return v;
}

// ================= K1: per teacher row: top-8 + weights (also zeroes out[0]) ==========
__global__ __launch_bounds__(NT) void k_topk(
    const float* __restrict__ teacher, const float* __restrict__ center,
    const int* __restrict__ epoch_p,
    int* __restrict__ idx_ws, float* __restrict__ p_ws, float* __restrict__ out)
{
    const int row = blockIdx.x;     // 0..511
    const int t = threadIdx.x;
    const int lane = t & 63, w = t >> 6;
    __shared__ float svv[8][4];
    __shared__ int   sii[8][4];

    if (row == 0 && t == 0) out[0] = 0.f;   // loss accumulator reset (before k_fin adds)

    const int e = epoch_p[0];
    const float temp = (e < 30) ? (0.04f + 0.03f * (float)e / 29.0f) : 0.07f;

    float z[32];
    const float* trow = teacher + (size_t)row * D;
    #pragma unroll
    for (int i = 0; i < 8; ++i) {
        const int d = i * 1024 + t * 4;
        float4 tv = *(const float4*)(trow + d);
        float4 cv = *(const float4*)(center + d);
        z[i*4+0] = tv.x - cv.x; z[i*4+1] = tv.y - cv.y;
        z[i*4+2] = tv.z - cv.z; z[i*4+3] = tv.w - cv.w;
    }

    float mvl = -INFINITY; int mil = 0;
    #pragma unroll
    for (int i = 0; i < 32; ++i)
        if (z[i] > mvl) { mvl = z[i]; mil = i; }

    float topv[8]; int topd[8];
    #pragma unroll 1
    for (int k = 0; k < 8; ++k) {
        float mv = mvl;
        int md = ((mil >> 2) << 10) + t * 4 + (mil & 3);
        #pragma unroll
        for (int o = 32; o > 0; o >>= 1) {
            float ov = __shfl_xor(mv, o, 64);
            int   od = __shfl_xor(md, o, 64);
            if (ov > mv) { mv = ov; md = od; }
        }
        if (lane == 0) { svv[k][w] = mv; sii[k][w] = md; }
        __syncthreads();
        float gv = svv[k][0]; int gd = sii[k][0];
        #pragma unroll
        for (int j = 1; j < 4; ++j)
            if (svv[k][j] > gv) { gv = svv[k][j]; gd = sii[k][j]; }
        topv[k] = gv; topd[k] = gd;
        if (((gd & 1023) >> 2) == t) {
            z[((gd >> 10) << 2) | (gd & 3)] = -INFINITY;
            mvl = -INFINITY; mil = 0;
            #pragma unroll
            for (int i = 0; i < 32; ++i)
                if (z[i] > mvl) { mvl = z[i]; mil = i; }
        }
    }

    if (t == 0) {
        float wgt[8]; float norm = 0.f;
        #pragma unroll
        for (int k = 0; k < 8; ++k) { wgt[k] = __expf((topv[k] - topv[0]) / temp); norm += wgt[k]; }
        const float invn = 1.0f / norm;
        #pragma unroll
        for (int k = 0; k < 8; ++k) {
            p_ws[row * 8 + k] = wgt[k] * invn;
            idx_ws[row * 8 + k] = topd[k];
        }
    }
}

// ===== K2 mega body: teacher row r side (iq = r<256 ? 0 : 1), chunk ch.
//       NV student partner rows (v = V0..V0+NV-1), dots computed directly vs pred chunks.
template<int NV, int V0>
__device__ __forceinline__ void mega_body(
    const int r, const int ch, const int t,
    const float* __restrict__ student, const float* __restrict__ pred,
    const int* __restrict__ idx_ws, const float* __restrict__ p_ws,
    float* __restrict__ part_lse, float* __restrict__ psA, float* __restrict__ psZ)
{
    const int lane = t & 63, w = t >> 6;
    const int b = r & 255;
    const int d0 = ch * 2048 + t * 4;
    __shared__ float sred[4][24];

    int jk[8]; float pk[8];
    #pragma unroll
    for (int k = 0; k < 8; ++k) {
        jk[k] = idx_ws[r * 8 + k];
        pk[k] = p_ws[r * 8 + k];
    }

    // student chunks -> y (exp'd; no max-subtraction: 10*s bounded, validated)
    float y[NV][8];
    #pragma unroll
    for (int vi = 0; vi < NV; ++vi) {
        const float* sp = student + (size_t)(256 * (V0 + vi) + b) * D + d0;
        float4 x0 = *(const float4*)sp;
        float4 x1 = *(const float4*)(sp + 1024);
        y[vi][0] = __expf(x0.x*10.f); y[vi][1] = __expf(x0.y*10.f);
        y[vi][2] = __expf(x0.z*10.f); y[vi][3] = __expf(x0.w*10.f);
        y[vi][4] = __expf(x1.x*10.f); y[vi][5] = __expf(x1.y*10.f);
        y[vi][6] = __expf(x1.z*10.f); y[vi][7] = __expf(x1.w*10.f);
    }
    float Zp[NV], acc[NV];
    #pragma unroll
    for (int vi = 0; vi < NV; ++vi) {
        Zp[vi] = y[vi][0]+y[vi][1]+y[vi][2]+y[vi][3]+y[vi][4]+y[vi][5]+y[vi][6]+y[vi][7];
        acc[vi] = 0.f;
    }

    float se[8];
    #pragma unroll
    for (int k = 0; k < 8; ++k) {
        const float* prow = pred + (size_t)jk[k] * D;
        float4 x0 = *(const float4*)(prow + d0);
        float4 x1 = *(const float4*)(prow + d0 + 1024);
        // 10*P bounded (~|1.2|) -> plain sum-exp is exact logsumexp
        se[k] = __expf(x0.x*10.f) + __expf(x0.y*10.f) + __expf(x0.z*10.f) + __expf(x0.w*10.f)
              + __expf(x1.x*10.f) + __expf(x1.y*10.f) + __expf(x1.z*10.f) + __expf(x1.w*10.f);
        const float p = pk[k];
        #pragma unroll
        for (int vi = 0; vi < NV; ++vi) {
            acc[vi] += p * (y[vi][0]*x0.x + y[vi][1]*x0.y + y[vi][2]*x0.z + y[vi][3]*x0.w
                          + y[vi][4]*x1.x + y[vi][5]*x1.y + y[vi][6]*x1.z + y[vi][7]*x1.w);
        }
    }

    // block reduction: se[8] + acc[NV] (+ Zp[NV] on iq0 side)
    #pragma unroll
    for (int k = 0; k < 8; ++k) se[k] = wave_sum(se[k]);
    #pragma unroll
    for (int vi = 0; vi < NV; ++vi) { acc[vi] = wave_sum(acc[vi]); }
    if constexpr (V0 == 1) {
        #pragma unroll
        for (int vi = 0; vi < NV; ++vi) Zp[vi] = wave_sum(Zp[vi]);
    }
    if (lane == 0) {
        #pragma unroll
        for (int k = 0; k < 8; ++k) sred[w][k] = se[k];
        #pragma unroll
        for (int vi = 0; vi < NV; ++vi) sred[w][8 + vi] = acc[vi];
        if constexpr (V0 == 1) {
            #pragma unroll
            for (int vi = 0; vi < NV; ++vi) sred[w][15 + vi] = Zp[vi];
        }
    }
    __syncthreads();
    if (t < 8)
        part_lse[(size_t)(r * 4 + ch) * 8 + t] =
            sred[0][t] + sred[1][t] + sred[2][t] + sred[3][t];
    if (t >= 8 && t < 8 + NV)
        psA[(size_t)(b * 4 + ch) * 8 + (t - 8)] =
            sred[0][t] + sred[1][t] + sred[2][t] + sred[3][t];
    if constexpr (V0 == 1) {
        if (t >= 15 && t < 22)
            psZ[(size_t)(b * 4 + ch) * 8 + (t - 15)] =
                sred[0][t] + sred[1][t] + sred[2][t] + sred[3][t];
    }
}

// ===== K2: blocks 0..2047 mega (r=bid>>2, ch=bid&3); blocks 2048..2175 colsum =====
__global__ __launch_bounds__(NT) void k_mega(
    const float* __restrict__ student, const float* __restrict__ pred,
    const int* __restrict__ idx_ws, const float* __restrict__ p_ws,
    const float* __restrict__ teacher,
    float* __restrict__ part_lse, float* __restrict__ psA0,
    float* __restrict__ psA1, float* __restrict__ psZ, float* __restrict__ part)
{
    const int bid = blockIdx.x;
    const int t = threadIdx.x;

    if (bid >= 2048) {
        // ---- colsum role ----
        const int cb = bid - 2048;
        const int rc = cb >> 3, dc = cb & 7;
        const int d0 = dc * 1024 + t * 4;
        const float* base = teacher + (size_t)rc * 32 * D + d0;
        float4 acc = make_float4(0.f, 0.f, 0.f, 0.f);
        #pragma unroll 4
        for (int r = 0; r < 32; ++r) {
            float4 x = *(const float4*)(base + (size_t)r * D);
            acc.x += x.x; acc.y += x.y; acc.z += x.z; acc.w += x.w;
        }
        *(float4*)(part + (size_t)rc * D + d0) = acc;
        return;
    }

    const int r = bid >> 2, ch = bid & 3;
    if (r < 256)
        mega_body<7, 1>(r, ch, t, student, pred, idx_ws, p_ws, part_lse, psA0, psZ);
    else
        mega_body<6, 2>(r, ch, t, student, pred, idx_ws, p_ws, part_lse, psA1, psZ);
}

// ==== K3: bids 0,1 = c-term finalize; bid 2 = center; bids 3..9 = student finalize ====
__global__ __launch_bounds__(NT) void k_fin(
    const float* __restrict__ p_ws, const float* __restrict__ part_lse,
    const float* __restrict__ part, const float* __restrict__ center,
    const float* __restrict__ psA0, const float* __restrict__ psA1,
    const float* __restrict__ psZ, float* __restrict__ out)
{
    const int bid = blockIdx.x;
    const int t = threadIdx.x;
    const int lane = t & 63, w = t >> 6;

    if (bid < 2) {
        // ---- c-term finalize: r = bid*256 + t; pair multiplicity 7 (iq=0) or 6 (iq=1) ----
        __shared__ float sm4[4];
        const int r = (bid << 8) | t;
        float c = 0.f;
        #pragma unroll
        for (int k = 0; k < 8; ++k) {
            float s = part_lse[(size_t)(r*4+0)*8+k] + part_lse[(size_t)(r*4+1)*8+k]
                    + part_lse[(size_t)(r*4+2)*8+k] + part_lse[(size_t)(r*4+3)*8+k];
            c += p_ws[r * 8 + k] * __logf(s);
        }
        const float wgt = (bid == 0) ? 7.0f : 6.0f;
        float vv = wave_sum(c * wgt * (1.0f / 3328.0f));
        if (lane == 0) sm4[w] = vv;
        __syncthreads();
        if (t == 0) atomicAdd(out, sm4[0] + sm4[1] + sm4[2] + sm4[3]);
        return;
    }

    if (bid == 2) {
        // ---- center: batch_center, EMA, entropies ----
        __shared__ float sm4[4];
        float c[32], bc[32];
        #pragma unroll
        for (int i = 0; i < 8; ++i) {
            const int d = i * 1024 + t * 4;
            float4 cv = *(const float4*)(center + d);
            float4 s = make_float4(0.f, 0.f, 0.f, 0.f);
            for (int rc = 0; rc < 16; ++rc) {
                float4 p = *(const float4*)(part + (size_t)rc * D + d);
                s.x += p.x; s.y += p.y; s.z += p.z; s.w += p.w;
            }
            const float sc = 1.0f / 512.0f;
            bc[i*4+0] = s.x * sc; bc[i*4+1] = s.y * sc;
            bc[i*4+2] = s.z * sc; bc[i*4+3] = s.w * sc;
            c[i*4+0] = cv.x; c[i*4+1] = cv.y; c[i*4+2] = cv.z; c[i*4+3] = cv.w;
            out[3 + d + 0] = cv.x * 0.9f + bc[i*4+0] * 0.1f;
            out[3 + d + 1] = cv.y * 0.9f + bc[i*4+1] * 0.1f;
            out[3 + d + 2] = cv.z * 0.9f + bc[i*4+2] * 0.1f;
            out[3 + d + 3] = cv.w * 0.9f + bc[i*4+3] * 0.1f;
        }

        float mc = -INFINITY, mb = -INFINITY;
        #pragma unroll
        for (int i = 0; i < 32; ++i) { mc = fmaxf(mc, c[i]); mb = fmaxf(mb, bc[i]); }
        #pragma unroll
        for (int o = 32; o > 0; o >>= 1) {
            mc = fmaxf(mc, __shfl_xor(mc, o, 64));
            mb = fmaxf(mb, __shfl_xor(mb, o, 64));
        }
        if (lane == 0) sm4[w] = mc;
        __syncthreads();
        mc = fmaxf(fmaxf(sm4[0], sm4[1]), fmaxf(sm4[2], sm4[3]));
        __syncthreads();
        if (lane == 0) sm4[w] = mb;
        __syncthreads();
        mb = fmaxf(fmaxf(sm4[0], sm4[1]), fmaxf(sm4[2], sm4[3]));
        __syncthreads();

        float zc = 0.f, zb = 0.f;
        #pragma unroll
        for (int i = 0; i < 32; ++i) { zc += __expf(c[i] - mc); zb += __expf(bc[i] - mb); }
        zc = wave_sum(zc); zb = wave_sum(zb);
        if (lane == 0) sm4[w] = zc;
        __syncthreads();
        zc = sm4[0] + sm4[1] + sm4[2] + sm4[3];
        __syncthreads();
        if (lane == 0) sm4[w] = zb;
        __syncthreads();
        zb = sm4[0] + sm4[1] + sm4[2] + sm4[3];
        __syncthreads();
        const float lnZc = __logf(zc);

        float te = 0.f, en = 0.f;
        #pragma unroll
        for (int i = 0; i < 32; ++i) {
            const float lsm = c[i] - mc - lnZc;
            te += __expf(c[i] - mc) * lsm;
            en += __expf(bc[i] - mb) * lsm;
        }
        te = wave_sum(te); en = wave_sum(en);
        if (lane == 0) sm4[w] = te;
        __syncthreads();
        te = sm4[0] + sm4[1] + sm4[2] + sm4[3];
        __syncthreads();
        if (lane == 0) sm4[w] = en;
        __syncthreads();
        en = sm4[0] + sm4[1] + sm4[2] + sm4[3];
        if (t == 0) {
            out[1] = en / zb;
            out[2] = te / zc;
        }
        return;
    }

    // ---- student finalize: g = (bid-3)*256 + t -> vi = g>>8 (v=vi+1), b = g&255 ----
    __shared__ float sm4[4];
    const int g = (bid - 3) * NT + t;   // 0..1791
    const int vi = g >> 8;              // 0..6
    const int b  = g & 255;
    const int v  = vi + 1;

    float Z = 0.f, A0 = 0.f, A1 = 0.f;
    #pragma unroll
    for (int ch = 0; ch < 4; ++ch) {
        const size_t base = (size_t)(b * 4 + ch) * 8;
        Z  += psZ [base + vi];
        A0 += psA0[base + vi];
        if (v >= 2) A1 += psA1[base + (v - 2)];
    }
    const float term = -10.f * (A0 + A1) / Z;
    float vv = wave_sum(term * (1.0f / 3328.0f));
    if (lane == 0) sm4[w] = vv;
    __syncthreads();
    if (t == 0) atomicAdd(out, sm4[0] + sm4[1] + sm4[2] + sm4[3]);
}

extern "C" void kernel_launch(void* const* d_in, const int* in_sizes, int n_in,
                              void* d_out, int out_size, void* d_ws, size_t ws_size,
                              hipStream_t stream) {
    const float* student = (const float*)d_in[0];
    const float* teacher = (const float*)d_in[1];
    const float* pred    = (const float*)d_in[2];
    const float* center  = (const float*)d_in[3];
    const int*   epoch   = (const int*)d_in[4];
    float* out = (float*)d_out;

    float* part     = (float*)d_ws;                     // 16*8192 f (512 KB)
    int*   idx_ws   = (int*)(part + (size_t)16 * D);    // 512*8 i
    float* p_ws     = (float*)(idx_ws + 512 * 8);       // 512*8 f
    float* part_lse = p_ws + 512 * 8;                   // 2048*8 f
    float* psA0     = part_lse + 2048 * 8;              // 1024*8 f
    float* psA1     = psA0 + 1024 * 8;                  // 1024*8 f
    float* psZ      = psA1 + 1024 * 8;                  // 1024*8 f

    k_topk<<<512, NT, 0, stream>>>(teacher, center, epoch, idx_ws, p_ws, out);
    k_mega<<<2176, NT, 0, stream>>>(student, pred, idx_ws, p_ws, teacher,
                                    part_lse, psA0, psA1, psZ, part);
    k_fin<<<10, NT, 0, stream>>>(p_ws, part_lse, part, center,
                                 psA0, psA1, psZ, out);
}